// Round 3
// baseline (515.091 us; speedup 1.0000x reference)
//
#include <hip/hip_runtime.h>
#include <hip/hip_bf16.h>

// ---------------------------------------------------------------------------
// CustomTransformerLayer: QKV proj -> unscaled single-head attn -> Wo -> LN1
//                         -> FF1(relu) -> FF2 -> LN2
// B=4, S=2048, E=1024, FF=4096.  GEMMs: fp16 MFMA 16x16x32, fp32 acc.
// Quadrant-phase pipelined schedule: 4-slot 32-K LDS ring, 2 phases/slab
// (16 MFMA each), register ds_reads issued one phase ahead, counted vmcnt.
// ---------------------------------------------------------------------------

using u16 = unsigned short;
typedef __attribute__((ext_vector_type(8))) _Float16 half8;
typedef __attribute__((ext_vector_type(4))) float f32x4;

#define BATCH 4
#define SEQ   2048
#define EMB   1024
#define FFD   4096

// byte-offset swizzle within a [row][64B] slab row: 16B-slot spread, 2-way max
#define SWZ(r) ((((r) >> 1) & 3) << 4)

__device__ __forceinline__ u16 f2h(float f) {
    union { _Float16 h; u16 u; } x;
    x.h = (_Float16)f;
    return x.u;
}
__device__ __forceinline__ float h2f(u16 u) {
    union { u16 u; _Float16 h; } x;
    x.u = u;
    return (float)x.h;
}

typedef const __attribute__((address_space(1))) void* gas_ptr;
typedef __attribute__((address_space(3))) void* las_ptr;

__device__ __forceinline__ void load_lds16(const void* g, void* l) {
    __builtin_amdgcn_global_load_lds((gas_ptr)g, (las_ptr)l, 16, 0, 0);
}

// ---------------------------------------------------------------------------
// GEMM:  C[M,N] = A[M,K] * Bt[N,K]^T  (+bias) (+relu)
// BM x 256 tile, 512 threads = 2x4 waves, wave tile (BM/2) x 64.
// ---------------------------------------------------------------------------
template <int BM, typename OutT, bool RELU, bool BIAS>
__global__ __launch_bounds__(512, 2) void gemm_dp(
    const u16* __restrict__ A, const u16* __restrict__ Bt,
    OutT* __restrict__ C, const float* __restrict__ bias,
    int N, int K, int lda, int ldb, int ldc, long sA, long sB, long sC)
{
    constexpr int MF = BM / 32;          // A frags per wave
    constexpr int MH = MF / 2;           // A frags per quadrant phase
    constexpr int AL = BM / 128;         // A stage instrs per slab
    constexpr int SLAB_A = BM * 32;      // elems per A slab
    constexpr int SLAB_B = 256 * 32;     // elems per B slab

    __shared__ u16 ldsA[4 * SLAB_A];
    __shared__ u16 ldsB[4 * SLAB_B];

    A  += (long)blockIdx.z * sA;
    Bt += (long)blockIdx.z * sB;
    C  += (long)blockIdx.z * sC;

    const int tid  = threadIdx.x;
    const int lane = tid & 63;
    const int wv   = tid >> 6;           // 0..7
    const int wm   = wv >> 2;            // 0..1
    const int wn   = wv & 3;             // 0..3
    const long row0 = (long)blockIdx.x * BM;
    const long col0 = (long)blockIdx.y * 256;

    // stage source (global elem offsets) / dest (slab byte offsets) ---------
    long aoff[AL]; int adst[AL];
#pragma unroll
    for (int i = 0; i < AL; ++i) {
        const int d16 = i * 512 + tid;
        const int row = d16 >> 2;
        const int colb = ((d16 & 3) << 4) ^ SWZ(row);   // pre-swizzled source
        aoff[i] = (row0 + row) * (long)lda + (colb >> 1);
        adst[i] = d16 * 16;
    }
    long boff[2]; int bdst[2];
#pragma unroll
    for (int i = 0; i < 2; ++i) {
        const int d16 = i * 512 + tid;
        const int row = d16 >> 2;
        const int colb = ((d16 & 3) << 4) ^ SWZ(row);
        boff[i] = (col0 + row) * (long)ldb + (colb >> 1);
        bdst[i] = d16 * 16;
    }

    // ds_read byte offsets (SWZ period 8 divides 16 -> frag step = 1024 B)
    const int klane = (lane >> 4) << 4;  // 0,16,32,48
    const int arow = wm * (BM / 2) + (lane & 15);
    const int aro0 = arow * 64 + (klane ^ SWZ(arow));
    const int brow = wn * 64 + (lane & 15);
    const int bro0 = brow * 64 + (klane ^ SWZ(brow));

    f32x4 acc[MF][4] = {};
    half8 Aa[MH], Ab[MH], Ba[4], Bb[4];
    const int G = K >> 5;                // 32-wide K slabs (even, >= 8 here)

    auto stage = [&](int g) {
        const int slot = g & 3;
        const long k0 = (long)g << 5;
#pragma unroll
        for (int i = 0; i < AL; ++i)
            load_lds16(A + aoff[i] + k0, (char*)ldsA + slot * (SLAB_A * 2) + adst[i]);
#pragma unroll
        for (int i = 0; i < 2; ++i)
            load_lds16(Bt + boff[i] + k0, (char*)ldsB + slot * (SLAB_B * 2) + bdst[i]);
    };

#define LDSA_P(slot) ((const char*)ldsA + (slot) * (SLAB_A * 2))
#define LDSB_P(slot) ((const char*)ldsB + (slot) * (SLAB_B * 2))
#define RD_A(dst, slot, mh)                                                   \
    _Pragma("unroll") for (int i_ = 0; i_ < MH; ++i_)                         \
        dst[i_] = *(const half8*)(LDSA_P(slot) + aro0 + ((mh) * MH + i_) * 1024);
#define RD_B(dst, slot)                                                       \
    _Pragma("unroll") for (int n_ = 0; n_ < 4; ++n_)                          \
        dst[n_] = *(const half8*)(LDSB_P(slot) + bro0 + n_ * 1024);
#define MM(Ax, Bx, mh)                                                        \
    __builtin_amdgcn_s_setprio(1);                                            \
    _Pragma("unroll") for (int i_ = 0; i_ < MH; ++i_)                         \
    _Pragma("unroll") for (int n_ = 0; n_ < 4; ++n_)                          \
        acc[(mh) * MH + i_][n_] = __builtin_amdgcn_mfma_f32_16x16x32_f16(     \
            Ax[i_], Bx[n_], acc[(mh) * MH + i_][n_], 0, 0, 0);                \
    __builtin_amdgcn_s_setprio(0);
#define BAR { __builtin_amdgcn_s_barrier(); __builtin_amdgcn_sched_barrier(0); }
#define VMS  { if constexpr (BM == 256) asm volatile("s_waitcnt vmcnt(8)" ::: "memory"); \
               else                     asm volatile("s_waitcnt vmcnt(6)" ::: "memory"); }
#define VMT  { if constexpr (BM == 256) asm volatile("s_waitcnt vmcnt(4)" ::: "memory"); \
               else                     asm volatile("s_waitcnt vmcnt(3)" ::: "memory"); }
#define VM0  asm volatile("s_waitcnt vmcnt(0)" ::: "memory")

    // prologue: slabs 0,1,2 staged; drain slab 0; load first quadrant regs
    stage(0); stage(1); stage(2);
    VMS; BAR;
    RD_A(Aa, 0, 0); RD_B(Ba, 0);

    // 4-phase pair: phases (s,0) (s,1) (s+1,0) (s+1,1); reads one phase ahead
#define PAIR(S, DOSTG0, VMA, DOSTG1, VMB)                                     \
    {                                                                         \
        if (DOSTG0) stage((S) + 3);                                           \
        RD_A(Ab, (S) & 3, 1); VMA; MM(Aa, Ba, 0); BAR;                        \
        RD_A(Aa, ((S) + 1) & 3, 0); RD_B(Bb, ((S) + 1) & 3);                  \
        MM(Ab, Ba, 1); BAR;                                                   \
        if (DOSTG1) stage((S) + 4);                                           \
        RD_A(Ab, ((S) + 1) & 3, 1); VMB; MM(Aa, Bb, 0); BAR;                  \
        RD_A(Aa, ((S) + 2) & 3, 0); RD_B(Ba, ((S) + 2) & 3);                  \
        MM(Ab, Bb, 1); BAR;                                                   \
    }

    for (int s = 0; s <= G - 6; s += 2) PAIR(s, true, VMS, true, VMS)
    PAIR(G - 4, true, VMS, false, VMT)
    // final pair (s = G-2): no staging, no reads past slab G-1
    RD_A(Ab, (G - 2) & 3, 1); VM0; MM(Aa, Ba, 0); BAR;
    RD_A(Aa, (G - 1) & 3, 0); RD_B(Bb, (G - 1) & 3); MM(Ab, Ba, 1); BAR;
    RD_A(Ab, (G - 1) & 3, 1); MM(Aa, Bb, 0); BAR;
    MM(Ab, Bb, 1);
#undef PAIR

    // epilogue: C/D layout col=lane&15, row=(lane>>4)*4+reg
#pragma unroll
    for (int n = 0; n < 4; ++n) {
        const long col = col0 + wn * 64 + n * 16 + (lane & 15);
        const float bv_ = BIAS ? bias[col] : 0.0f;
#pragma unroll
        for (int m = 0; m < MF; ++m) {
            const long row = row0 + wm * (BM / 2) + m * 16 + ((lane >> 4) << 2);
#pragma unroll
            for (int r = 0; r < 4; ++r) {
                float v = acc[m][n][r] + bv_;
                if (RELU) v = fmaxf(v, 0.0f);
                if constexpr (sizeof(OutT) == 2)
                    C[(row + r) * (long)ldc + col] = f2h(v);
                else
                    C[(row + r) * (long)ldc + col] = v;
            }
        }
    }
#undef LDSA_P
#undef LDSB_P
#undef RD_A
#undef RD_B
#undef MM
#undef BAR
#undef VMS
#undef VMT
#undef VM0
}

// ---------------------------------------------------------------------------
// fp32 [R,C] -> fp16 [C,R] transpose (weights)
// ---------------------------------------------------------------------------
__global__ __launch_bounds__(256) void transpose_cast(
    const float* __restrict__ in, u16* __restrict__ out, int R, int C)
{
    __shared__ float t[32][33];
    const int bc = blockIdx.x * 32, br = blockIdx.y * 32;
    const int lx = threadIdx.x & 31, ly = threadIdx.x >> 5;
#pragma unroll
    for (int i = 0; i < 32; i += 8)
        t[ly + i][lx] = in[(long)(br + ly + i) * C + bc + lx];
    __syncthreads();
#pragma unroll
    for (int i = 0; i < 32; i += 8)
        out[(long)(bc + ly + i) * R + br + lx] = f2h(t[lx][ly + i]);
}

// fp16 [R,C] (ldin) -> fp16 [C,R] (ldout) transpose, batched over z
__global__ __launch_bounds__(256) void transpose_h(
    const u16* __restrict__ in, u16* __restrict__ out,
    int ldin, int ldout, long sIn, long sOut)
{
    __shared__ u16 t[32][33];
    in  += (long)blockIdx.z * sIn;
    out += (long)blockIdx.z * sOut;
    const int bc = blockIdx.x * 32, br = blockIdx.y * 32;
    const int lx = threadIdx.x & 31, ly = threadIdx.x >> 5;
#pragma unroll
    for (int i = 0; i < 32; i += 8)
        t[ly + i][lx] = in[(long)(br + ly + i) * ldin + bc + lx];
    __syncthreads();
#pragma unroll
    for (int i = 0; i < 32; i += 8)
        out[(long)(bc + ly + i) * ldout + br + lx] = t[lx][ly + i];
}

// fp32 -> fp16 elementwise cast, 8 elems/thread
__global__ __launch_bounds__(256) void cast_h(
    const float* __restrict__ in, u16* __restrict__ out)
{
    const long i = ((long)blockIdx.x * 256 + threadIdx.x) * 8;
    const float4 a = ((const float4*)(in + i))[0];
    const float4 b = ((const float4*)(in + i))[1];
    union { u16 u[8]; uint4 v; } pk;
    pk.u[0] = f2h(a.x); pk.u[1] = f2h(a.y); pk.u[2] = f2h(a.z); pk.u[3] = f2h(a.w);
    pk.u[4] = f2h(b.x); pk.u[5] = f2h(b.y); pk.u[6] = f2h(b.z); pk.u[7] = f2h(b.w);
    *(uint4*)(out + i) = pk.v;
}

// bias concat: [bq|bk|bv] -> 3072 fp32
__global__ __launch_bounds__(256) void concat_bias(
    const float* __restrict__ bq, const float* __restrict__ bk,
    const float* __restrict__ bv, float* __restrict__ o)
{
    const int i = blockIdx.x * 256 + threadIdx.x;
    o[i] = i < 1024 ? bq[i] : (i < 2048 ? bk[i - 1024] : bv[i - 2048]);
}

// ---------------------------------------------------------------------------
// row softmax: fp16 [rows,2048] -> fp16 [rows,2048], one block per row
// ---------------------------------------------------------------------------
__global__ __launch_bounds__(256) void softmax_kernel(
    const u16* __restrict__ S, u16* __restrict__ P)
{
    const long row = blockIdx.x;
    const int tid = threadIdx.x;

    union { uint4 v; u16 u[8]; } in;
    in.v = ((const uint4*)(S + row * SEQ))[tid];
    float f[8];
#pragma unroll
    for (int j = 0; j < 8; ++j) f[j] = h2f(in.u[j]);

    float m = fmaxf(fmaxf(fmaxf(f[0], f[1]), fmaxf(f[2], f[3])),
                    fmaxf(fmaxf(f[4], f[5]), fmaxf(f[6], f[7])));
#pragma unroll
    for (int off = 32; off; off >>= 1) m = fmaxf(m, __shfl_xor(m, off));

    __shared__ float rm[4], rs[4];
    if ((tid & 63) == 0) rm[tid >> 6] = m;
    __syncthreads();
    m = fmaxf(fmaxf(rm[0], rm[1]), fmaxf(rm[2], rm[3]));

    float e[8], s = 0.0f;
#pragma unroll
    for (int j = 0; j < 8; ++j) { e[j] = expf(f[j] - m); s += e[j]; }
#pragma unroll
    for (int off = 32; off; off >>= 1) s += __shfl_xor(s, off);
    if ((tid & 63) == 0) rs[tid >> 6] = s;
    __syncthreads();
    s = (rs[0] + rs[1]) + (rs[2] + rs[3]);

    const float inv = 1.0f / s;
    union { u16 u[8]; uint4 v; } pk;
#pragma unroll
    for (int j = 0; j < 8; ++j) pk.u[j] = f2h(e[j] * inv);
    *(uint4*)(P + row * SEQ + tid * 8) = pk.v;
}

// ---------------------------------------------------------------------------
// fused residual + layernorm; writes fp32 Xout and optional fp16 Xh
// ---------------------------------------------------------------------------
__global__ __launch_bounds__(256) void ln_kernel(
    const float* __restrict__ Ain, const float* __restrict__ Bin,
    const float* __restrict__ g, const float* __restrict__ be,
    float* __restrict__ Xout, u16* __restrict__ Xh)
{
    const long row = blockIdx.x;
    const int tid = threadIdx.x;

    const float4 a = ((const float4*)(Ain + row * EMB))[tid];
    const float4 b = ((const float4*)(Bin + row * EMB))[tid];
    const float h0 = a.x + b.x, h1 = a.y + b.y, h2 = a.z + b.z, h3 = a.w + b.w;

    float s = (h0 + h1) + (h2 + h3);
    float q = (h0 * h0 + h1 * h1) + (h2 * h2 + h3 * h3);
#pragma unroll
    for (int off = 32; off; off >>= 1) {
        s += __shfl_xor(s, off);
        q += __shfl_xor(q, off);
    }
    __shared__ float rsm[4], rqm[4];
    if ((tid & 63) == 0) { rsm[tid >> 6] = s; rqm[tid >> 6] = q; }
    __syncthreads();
    s = (rsm[0] + rsm[1]) + (rsm[2] + rsm[3]);
    q = (rqm[0] + rqm[1]) + (rqm[2] + rqm[3]);

    const float mu  = s * (1.0f / EMB);
    const float var = q * (1.0f / EMB) - mu * mu;
    const float rstd = rsqrtf(var + 1e-5f);

    const float4 gv = ((const float4*)g)[tid];
    const float4 bv = ((const float4*)be)[tid];
    const float y0 = (h0 - mu) * rstd * gv.x + bv.x;
    const float y1 = (h1 - mu) * rstd * gv.y + bv.y;
    const float y2 = (h2 - mu) * rstd * gv.z + bv.z;
    const float y3 = (h3 - mu) * rstd * gv.w + bv.w;

    ((float4*)(Xout + row * EMB))[tid] = make_float4(y0, y1, y2, y3);
    if (Xh) {
        union { u16 u[4]; uint2 v; } pk;
        pk.u[0] = f2h(y0); pk.u[1] = f2h(y1);
        pk.u[2] = f2h(y2); pk.u[3] = f2h(y3);
        ((uint2*)(Xh + row * EMB))[tid] = pk.v;
    }
}

// ---------------------------------------------------------------------------
extern "C" void kernel_launch(void* const* d_in, const int* in_sizes, int n_in,
                              void* d_out, int out_size, void* d_ws, size_t ws_size,
                              hipStream_t stream)
{
    const float* src = (const float*)d_in[0];
    const float* Wq  = (const float*)d_in[1];
    const float* bq  = (const float*)d_in[2];
    const float* Wk  = (const float*)d_in[3];
    const float* bk  = (const float*)d_in[4];
    const float* Wv  = (const float*)d_in[5];
    const float* bv  = (const float*)d_in[6];
    const float* Wo  = (const float*)d_in[7];
    const float* bo  = (const float*)d_in[8];
    const float* W1  = (const float*)d_in[9];
    const float* b1  = (const float*)d_in[10];
    const float* W2  = (const float*)d_in[11];
    const float* b2  = (const float*)d_in[12];
    const float* g1  = (const float*)d_in[13];
    const float* be1 = (const float*)d_in[14];
    const float* g2  = (const float*)d_in[15];
    const float* be2 = (const float*)d_in[16];
    float* out = (float*)d_out;

    char* ws = (char*)d_ws;
    const size_t MB = 1ull << 20;
    // persistent fp16 weights
    u16*   WqkvT   = (u16*)  (ws + 0 * MB);    // [3072,1024] 6MB
    u16*   WoT     = (u16*)  (ws + 6 * MB);    // [1024,1024] 2MB
    u16*   W1T     = (u16*)  (ws + 8 * MB);    // [4096,1024] 8MB
    u16*   W2T     = (u16*)  (ws + 16 * MB);   // [1024,4096] 8MB
    float* bqkv    = (float*)(ws + 24 * MB);   // [3072]
    u16*   Xh      = (u16*)  (ws + 25 * MB);   // [8192,1024] 16MB
    u16*   QKVh    = (u16*)  (ws + 41 * MB);   // [8192,3072] 48MB
    u16*   Vt      = (u16*)  (ws + 89 * MB);   // [4,1024,2048] 16MB
    u16*   scoresh = (u16*)  (ws + 105 * MB);  // [4,2048,2048] fp16 32MB
    u16*   P       = (u16*)  (ws + 137 * MB);  // [4,2048,2048] fp16 32MB
    u16*   attn    = (u16*)  (ws + 105 * MB);  // 16MB (scores dead after softmax)
    float* attnp   = (float*)(ws + 121 * MB);  // 32MB fp32 (P dead after PV? no:
                                               //  attnp written at Wo, P dead then)
    float* x       = (float*)(ws + 153 * MB);  // 32MB fp32 (P dead)
    u16*   xh      = (u16*)  (ws + 41 * MB);   // 16MB (QKVh dead after scores/Vt)
    u16*   ff1     = (u16*)  (ws + 57 * MB);   // [8192,4096] 64MB (57..121, all dead)
    float* ff2     = (float*)(ws + 121 * MB);  // 32MB fp32 (attnp dead after LN1)
    // peak: 185MB

    const int M = BATCH * SEQ;                 // 8192
    const long SS = (long)SEQ * SEQ;           // 4M

    // 1) weights -> fp16 transposed (QKV concat into [3072,1024])
    transpose_cast<<<dim3(32, 32, 1), 256, 0, stream>>>(Wq, WqkvT, EMB, EMB);
    transpose_cast<<<dim3(32, 32, 1), 256, 0, stream>>>(Wk, WqkvT + 1024 * 1024, EMB, EMB);
    transpose_cast<<<dim3(32, 32, 1), 256, 0, stream>>>(Wv, WqkvT + 2048 * 1024, EMB, EMB);
    transpose_cast<<<dim3(32, 32, 1), 256, 0, stream>>>(Wo, WoT, EMB, EMB);
    transpose_cast<<<dim3(128, 32, 1), 256, 0, stream>>>(W1, W1T, EMB, FFD);
    transpose_cast<<<dim3(32, 128, 1), 256, 0, stream>>>(W2, W2T, FFD, EMB);
    concat_bias<<<dim3(12), 256, 0, stream>>>(bq, bk, bv, bqkv);

    // 2) src -> fp16
    cast_h<<<dim3((M * EMB) / (256 * 8)), 256, 0, stream>>>(src, Xh);

    // 3) fused QKV projection  [8192,3072]
    gemm_dp<256, u16, false, true><<<dim3(32, 12, 1), 512, 0, stream>>>(
        Xh, WqkvT, QKVh, bqkv, 3072, 1024, 1024, 1024, 3072, 0, 0, 0);

    // 4) V -> Vt [B,E,S]
    transpose_h<<<dim3(32, 64, BATCH), 256, 0, stream>>>(
        QKVh + 2048, Vt, 3072, SEQ, (long)SEQ * 3072, (long)EMB * SEQ);

    // 5) scores = Q @ K^T per batch (fp16 out)
    gemm_dp<256, u16, false, false><<<dim3(8, 8, BATCH), 512, 0, stream>>>(
        QKVh, QKVh + 1024, scoresh, nullptr, SEQ, EMB, 3072, 3072, SEQ,
        (long)SEQ * 3072, (long)SEQ * 3072, SS);

    // 6) softmax -> P fp16
    softmax_kernel<<<dim3(M), 256, 0, stream>>>(scoresh, P);

    // 7) attn = P @ Vt^T per batch
    gemm_dp<128, u16, false, false><<<dim3(16, 4, BATCH), 512, 0, stream>>>(
        P, Vt, attn, nullptr, EMB, SEQ, SEQ, SEQ, EMB,
        SS, (long)EMB * SEQ, (long)SEQ * EMB);

    // 8) attnp = attn @ Wo^T + bo
    gemm_dp<128, float, false, true><<<dim3(64, 4, 1), 512, 0, stream>>>(
        attn, WoT, attnp, bo, EMB, EMB, EMB, EMB, EMB, 0, 0, 0);

    // 9) x = LN1(src + attnp); also xh fp16
    ln_kernel<<<dim3(M), 256, 0, stream>>>(src, attnp, g1, be1, x, xh);

    // 10) ff1 = relu(x @ W1^T + b1)
    gemm_dp<256, u16, true, true><<<dim3(32, 16, 1), 512, 0, stream>>>(
        xh, W1T, ff1, b1, FFD, EMB, EMB, EMB, FFD, 0, 0, 0);

    // 11) ff2 = ff1 @ W2^T + b2
    gemm_dp<128, float, false, true><<<dim3(64, 4, 1), 512, 0, stream>>>(
        ff1, W2T, ff2, b2, EMB, FFD, FFD, FFD, EMB, 0, 0, 0);

    // 12) out = LN2(x + ff2)
    ln_kernel<<<dim3(M), 256, 0, stream>>>(x, ff2, g2, be2, out, nullptr);
}

// Round 4
// 459.597 us; speedup vs baseline: 1.1207x; 1.1207x over previous
//
#include <hip/hip_runtime.h>
#include <hip/hip_bf16.h>

// ---------------------------------------------------------------------------
// CustomTransformerLayer: QKV proj -> unscaled single-head attn -> Wo -> LN1
//                         -> FF1(relu) -> FF2 -> LN2
// B=4, S=2048, E=1024, FF=4096.  GEMMs: fp16 MFMA 16x16x32, fp32 acc.
//  - gemm_q (BM=256): quadrant-phase pipeline, 2 phases/slab, 16 MFMA/phase,
//    register reads one phase ahead, counted vmcnt.   [round-3 winner]
//  - gemm_s (BM=128): single-phase/slab, 16 MFMA, 1 barrier/slab. [round-2]
// ---------------------------------------------------------------------------

using u16 = unsigned short;
typedef __attribute__((ext_vector_type(8))) _Float16 half8;
typedef __attribute__((ext_vector_type(4))) float f32x4;

#define BATCH 4
#define SEQ   2048
#define EMB   1024
#define FFD   4096

// byte-offset swizzle within a [row][64B] slab row: 16B-slot spread, 2-way max
#define SWZ(r) ((((r) >> 1) & 3) << 4)

__device__ __forceinline__ u16 f2h(float f) {
    union { _Float16 h; u16 u; } x;
    x.h = (_Float16)f;
    return x.u;
}
__device__ __forceinline__ float h2f(u16 u) {
    union { u16 u; _Float16 h; } x;
    x.u = u;
    return (float)x.h;
}

typedef const __attribute__((address_space(1))) void* gas_ptr;
typedef __attribute__((address_space(3))) void* las_ptr;

__device__ __forceinline__ void load_lds16(const void* g, void* l) {
    __builtin_amdgcn_global_load_lds((gas_ptr)g, (las_ptr)l, 16, 0, 0);
}

// ---------------------------------------------------------------------------
// gemm_q:  C[M,N] = A[M,K] * Bt[N,K]^T  (+bias) (+relu)    BM=256 x 256 tile
// 512 threads = 2x4 waves, wave tile 128 x 64.  Quadrant-phase pipeline.
// ---------------------------------------------------------------------------
template <int BM, typename OutT, bool RELU, bool BIAS>
__global__ __launch_bounds__(512, 2) void gemm_q(
    const u16* __restrict__ A, const u16* __restrict__ Bt,
    OutT* __restrict__ C, const float* __restrict__ bias,
    int N, int K, int lda, int ldb, int ldc, long sA, long sB, long sC)
{
    constexpr int MF = BM / 32;          // A frags per wave (8)
    constexpr int MH = MF / 2;           // A frags per quadrant phase (4)
    constexpr int AL = BM / 128;         // A stage instrs per slab (2)
    constexpr int SLAB_A = BM * 32;
    constexpr int SLAB_B = 256 * 32;

    __shared__ u16 ldsA[4 * SLAB_A];
    __shared__ u16 ldsB[4 * SLAB_B];

    A  += (long)blockIdx.z * sA;
    Bt += (long)blockIdx.z * sB;
    C  += (long)blockIdx.z * sC;

    const int tid  = threadIdx.x;
    const int lane = tid & 63;
    const int wv   = tid >> 6;
    const int wm   = wv >> 2;
    const int wn   = wv & 3;
    const long row0 = (long)blockIdx.x * BM;
    const long col0 = (long)blockIdx.y * 256;

    long aoff[AL]; int adst[AL];
#pragma unroll
    for (int i = 0; i < AL; ++i) {
        const int d16 = i * 512 + tid;
        const int row = d16 >> 2;
        const int colb = ((d16 & 3) << 4) ^ SWZ(row);
        aoff[i] = (row0 + row) * (long)lda + (colb >> 1);
        adst[i] = d16 * 16;
    }
    long boff[2]; int bdst[2];
#pragma unroll
    for (int i = 0; i < 2; ++i) {
        const int d16 = i * 512 + tid;
        const int row = d16 >> 2;
        const int colb = ((d16 & 3) << 4) ^ SWZ(row);
        boff[i] = (col0 + row) * (long)ldb + (colb >> 1);
        bdst[i] = d16 * 16;
    }

    const int klane = (lane >> 4) << 4;
    const int arow = wm * (BM / 2) + (lane & 15);
    const int aro0 = arow * 64 + (klane ^ SWZ(arow));
    const int brow = wn * 64 + (lane & 15);
    const int bro0 = brow * 64 + (klane ^ SWZ(brow));

    f32x4 acc[MF][4] = {};
    half8 Aa[MH], Ab[MH], Ba[4], Bb[4];
    const int G = K >> 5;

    auto stage = [&](int g) {
        const int slot = g & 3;
        const long k0 = (long)g << 5;
#pragma unroll
        for (int i = 0; i < AL; ++i)
            load_lds16(A + aoff[i] + k0, (char*)ldsA + slot * (SLAB_A * 2) + adst[i]);
#pragma unroll
        for (int i = 0; i < 2; ++i)
            load_lds16(Bt + boff[i] + k0, (char*)ldsB + slot * (SLAB_B * 2) + bdst[i]);
    };

#define LDSA_P(slot) ((const char*)ldsA + (slot) * (SLAB_A * 2))
#define LDSB_P(slot) ((const char*)ldsB + (slot) * (SLAB_B * 2))
#define RD_A(dst, slot, mh)                                                   \
    _Pragma("unroll") for (int i_ = 0; i_ < MH; ++i_)                         \
        dst[i_] = *(const half8*)(LDSA_P(slot) + aro0 + ((mh) * MH + i_) * 1024);
#define RD_B(dst, slot)                                                       \
    _Pragma("unroll") for (int n_ = 0; n_ < 4; ++n_)                          \
        dst[n_] = *(const half8*)(LDSB_P(slot) + bro0 + n_ * 1024);
#define MM(Ax, Bx, mh)                                                        \
    __builtin_amdgcn_s_setprio(1);                                            \
    _Pragma("unroll") for (int i_ = 0; i_ < MH; ++i_)                         \
    _Pragma("unroll") for (int n_ = 0; n_ < 4; ++n_)                          \
        acc[(mh) * MH + i_][n_] = __builtin_amdgcn_mfma_f32_16x16x32_f16(     \
            Ax[i_], Bx[n_], acc[(mh) * MH + i_], 0, 0, 0)[0 * 0],             \
    (void)0;                                                                  \
    __builtin_amdgcn_s_setprio(0);
#undef MM
#define MM(Ax, Bx, mh)                                                        \
    __builtin_amdgcn_s_setprio(1);                                            \
    _Pragma("unroll") for (int i_ = 0; i_ < MH; ++i_)                         \
    _Pragma("unroll") for (int n_ = 0; n_ < 4; ++n_)                          \
        acc[(mh) * MH + i_][n_] = __builtin_amdgcn_mfma_f32_16x16x32_f16(     \
            Ax[i_], Bx[n_], acc[(mh) * MH + i_][n_], 0, 0, 0);                \
    __builtin_amdgcn_s_setprio(0);
#define BAR { __builtin_amdgcn_s_barrier(); __builtin_amdgcn_sched_barrier(0); }
#define VMS  asm volatile("s_waitcnt vmcnt(8)" ::: "memory")
#define VMT  asm volatile("s_waitcnt vmcnt(4)" ::: "memory")
#define VM0  asm volatile("s_waitcnt vmcnt(0)" ::: "memory")

    stage(0); stage(1); stage(2);
    VMS; BAR;
    RD_A(Aa, 0, 0); RD_B(Ba, 0);

#define PAIR(S, DOSTG0, VMA, DOSTG1, VMB)                                     \
    {                                                                         \
        if (DOSTG0) stage((S) + 3);                                           \
        RD_A(Ab, (S) & 3, 1); VMA; MM(Aa, Ba, 0); BAR;                        \
        RD_A(Aa, ((S) + 1) & 3, 0); RD_B(Bb, ((S) + 1) & 3);                  \
        MM(Ab, Ba, 1); BAR;                                                   \
        if (DOSTG1) stage((S) + 4);                                           \
        RD_A(Ab, ((S) + 1) & 3, 1); VMB; MM(Aa, Bb, 0); BAR;                  \
        RD_A(Aa, ((S) + 2) & 3, 0); RD_B(Ba, ((S) + 2) & 3);                  \
        MM(Ab, Bb, 1); BAR;                                                   \
    }

    for (int s = 0; s <= G - 6; s += 2) PAIR(s, true, VMS, true, VMS)
    PAIR(G - 4, true, VMS, false, VMT)
    RD_A(Ab, (G - 2) & 3, 1); VM0; MM(Aa, Ba, 0); BAR;
    RD_A(Aa, (G - 1) & 3, 0); RD_B(Bb, (G - 1) & 3); MM(Ab, Ba, 1); BAR;
    RD_A(Ab, (G - 1) & 3, 1); MM(Aa, Bb, 0); BAR;
    MM(Ab, Bb, 1);
#undef PAIR

#pragma unroll
    for (int n = 0; n < 4; ++n) {
        const long col = col0 + wn * 64 + n * 16 + (lane & 15);
        const float bv_ = BIAS ? bias[col] : 0.0f;
#pragma unroll
        for (int m = 0; m < MF; ++m) {
            const long row = row0 + wm * (BM / 2) + m * 16 + ((lane >> 4) << 2);
#pragma unroll
            for (int r = 0; r < 4; ++r) {
                float v = acc[m][n][r] + bv_;
                if (RELU) v = fmaxf(v, 0.0f);
                if constexpr (sizeof(OutT) == 2)
                    C[(row + r) * (long)ldc + col] = f2h(v);
                else
                    C[(row + r) * (long)ldc + col] = v;
            }
        }
    }
#undef LDSA_P
#undef LDSB_P
#undef RD_A
#undef RD_B
#undef MM
#undef BAR
#undef VMS
#undef VMT
#undef VM0
}

// ---------------------------------------------------------------------------
// gemm_s:  BM=128 x 256 tile, single phase per slab (round-2 schedule).
// ---------------------------------------------------------------------------
template <int BM, typename OutT, bool RELU, bool BIAS>
__global__ __launch_bounds__(512, 2) void gemm_s(
    const u16* __restrict__ A, const u16* __restrict__ Bt,
    OutT* __restrict__ C, const float* __restrict__ bias,
    int N, int K, int lda, int ldb, int ldc, long sA, long sB, long sC)
{
    constexpr int MF = BM / 32;          // 4
    constexpr int AL = BM / 128;         // 1
    constexpr int SLAB_A = BM * 32;
    constexpr int SLAB_B = 256 * 32;

    __shared__ u16 ldsA[4 * SLAB_A];
    __shared__ u16 ldsB[4 * SLAB_B];

    A  += (long)blockIdx.z * sA;
    Bt += (long)blockIdx.z * sB;
    C  += (long)blockIdx.z * sC;

    const int tid  = threadIdx.x;
    const int lane = tid & 63;
    const int wv   = tid >> 6;
    const int wm   = wv >> 2;
    const int wn   = wv & 3;
    const long row0 = (long)blockIdx.x * BM;
    const long col0 = (long)blockIdx.y * 256;

    long aoff[AL]; int adst[AL];
#pragma unroll
    for (int i = 0; i < AL; ++i) {
        const int d16 = i * 512 + tid;
        const int row = d16 >> 2;
        const int colb = ((d16 & 3) << 4) ^ SWZ(row);
        aoff[i] = (row0 + row) * (long)lda + (colb >> 1);
        adst[i] = d16 * 16;
    }
    long boff[2]; int bdst[2];
#pragma unroll
    for (int i = 0; i < 2; ++i) {
        const int d16 = i * 512 + tid;
        const int row = d16 >> 2;
        const int colb = ((d16 & 3) << 4) ^ SWZ(row);
        boff[i] = (col0 + row) * (long)ldb + (colb >> 1);
        bdst[i] = d16 * 16;
    }

    int aro[MF], bro[4];
    const int klane = (lane >> 4) << 4;
#pragma unroll
    for (int m = 0; m < MF; ++m) {
        const int row = wm * (BM / 2) + m * 16 + (lane & 15);
        aro[m] = row * 64 + (klane ^ SWZ(row));
    }
#pragma unroll
    for (int n = 0; n < 4; ++n) {
        const int row = wn * 64 + n * 16 + (lane & 15);
        bro[n] = row * 64 + (klane ^ SWZ(row));
    }

    f32x4 acc[MF][4] = {};
    const int G = K >> 5;

    auto stage = [&](int g) {
        const int slot = g & 3;
        const long k0 = (long)g << 5;
#pragma unroll
        for (int i = 0; i < AL; ++i)
            load_lds16(A + aoff[i] + k0, (char*)ldsA + slot * (SLAB_A * 2) + adst[i]);
#pragma unroll
        for (int i = 0; i < 2; ++i)
            load_lds16(Bt + boff[i] + k0, (char*)ldsB + slot * (SLAB_B * 2) + bdst[i]);
    };

#define VMS asm volatile("s_waitcnt vmcnt(6)" ::: "memory")
#define VMT asm volatile("s_waitcnt vmcnt(3)" ::: "memory")
#define VM0 asm volatile("s_waitcnt vmcnt(0)" ::: "memory")
#define VMNONE ((void)0)

#define GBODY(g, VMASM, DOSTAGE)                                              \
    {                                                                         \
        const int slot_ = (g) & 3;                                            \
        const char* abase_ = (const char*)ldsA + slot_ * (SLAB_A * 2);        \
        const char* bbase_ = (const char*)ldsB + slot_ * (SLAB_B * 2);        \
        half8 a_[MF], b_[4];                                                  \
        _Pragma("unroll") for (int m = 0; m < MF; ++m)                        \
            a_[m] = *(const half8*)(abase_ + aro[m]);                         \
        _Pragma("unroll") for (int n = 0; n < 4; ++n)                         \
            b_[n] = *(const half8*)(bbase_ + bro[n]);                         \
        if (DOSTAGE) stage((g) + 3);                                          \
        VMASM;                                                                \
        __builtin_amdgcn_s_setprio(1);                                        \
        _Pragma("unroll") for (int m = 0; m < MF; ++m)                        \
            _Pragma("unroll") for (int n = 0; n < 4; ++n)                     \
                acc[m][n] = __builtin_amdgcn_mfma_f32_16x16x32_f16(           \
                    a_[m], b_[n], acc[m][n], 0, 0, 0);                        \
        __builtin_amdgcn_s_setprio(0);                                        \
        __builtin_amdgcn_s_barrier();                                         \
        __builtin_amdgcn_sched_barrier(0);                                    \
    }

    stage(0); stage(1); stage(2);
    VMS;
    __builtin_amdgcn_s_barrier();
    __builtin_amdgcn_sched_barrier(0);

    for (int g = 0; g < G - 3; ++g) GBODY(g, VMS, true)
    GBODY(G - 3, VMT, false)
    GBODY(G - 2, VM0, false)
    GBODY(G - 1, VMNONE, false)
#undef GBODY
#undef VMS
#undef VMT
#undef VM0
#undef VMNONE

#pragma unroll
    for (int n = 0; n < 4; ++n) {
        const long col = col0 + wn * 64 + n * 16 + (lane & 15);
        const float bv_ = BIAS ? bias[col] : 0.0f;
#pragma unroll
        for (int m = 0; m < MF; ++m) {
            const long row = row0 + wm * (BM / 2) + m * 16 + ((lane >> 4) << 2);
#pragma unroll
            for (int r = 0; r < 4; ++r) {
                float v = acc[m][n][r] + bv_;
                if (RELU) v = fmaxf(v, 0.0f);
                if constexpr (sizeof(OutT) == 2)
                    C[(row + r) * (long)ldc + col] = f2h(v);
                else
                    C[(row + r) * (long)ldc + col] = v;
            }
        }
    }
}

// ---------------------------------------------------------------------------
// fp32 [R,C] -> fp16 [C,R] transpose (weights)
// ---------------------------------------------------------------------------
__global__ __launch_bounds__(256) void transpose_cast(
    const float* __restrict__ in, u16* __restrict__ out, int R, int C)
{
    __shared__ float t[32][33];
    const int bc = blockIdx.x * 32, br = blockIdx.y * 32;
    const int lx = threadIdx.x & 31, ly = threadIdx.x >> 5;
#pragma unroll
    for (int i = 0; i < 32; i += 8)
        t[ly + i][lx] = in[(long)(br + ly + i) * C + bc + lx];
    __syncthreads();
#pragma unroll
    for (int i = 0; i < 32; i += 8)
        out[(long)(bc + ly + i) * R + br + lx] = f2h(t[lx][ly + i]);
}

// fp16 [R,C] (ldin) -> fp16 [C,R] (ldout) transpose, batched over z
__global__ __launch_bounds__(256) void transpose_h(
    const u16* __restrict__ in, u16* __restrict__ out,
    int ldin, int ldout, long sIn, long sOut)
{
    __shared__ u16 t[32][33];
    in  += (long)blockIdx.z * sIn;
    out += (long)blockIdx.z * sOut;
    const int bc = blockIdx.x * 32, br = blockIdx.y * 32;
    const int lx = threadIdx.x & 31, ly = threadIdx.x >> 5;
#pragma unroll
    for (int i = 0; i < 32; i += 8)
        t[ly + i][lx] = in[(long)(br + ly + i) * ldin + bc + lx];
    __syncthreads();
#pragma unroll
    for (int i = 0; i < 32; i += 8)
        out[(long)(bc + ly + i) * ldout + br + lx] = t[lx][ly + i];
}

// fp32 -> fp16 elementwise cast, 8 elems/thread
__global__ __launch_bounds__(256) void cast_h(
    const float* __restrict__ in, u16* __restrict__ out)
{
    const long i = ((long)blockIdx.x * 256 + threadIdx.x) * 8;
    const float4 a = ((const float4*)(in + i))[0];
    const float4 b = ((const float4*)(in + i))[1];
    union { u16 u[8]; uint4 v; } pk;
    pk.u[0] = f2h(a.x); pk.u[1] = f2h(a.y); pk.u[2] = f2h(a.z); pk.u[3] = f2h(a.w);
    pk.u[4] = f2h(b.x); pk.u[5] = f2h(b.y); pk.u[6] = f2h(b.z); pk.u[7] = f2h(b.w);
    *(uint4*)(out + i) = pk.v;
}

// bias concat: [bq|bk|bv] -> 3072 fp32
__global__ __launch_bounds__(256) void concat_bias(
    const float* __restrict__ bq, const float* __restrict__ bk,
    const float* __restrict__ bv, float* __restrict__ o)
{
    const int i = blockIdx.x * 256 + threadIdx.x;
    o[i] = i < 1024 ? bq[i] : (i < 2048 ? bk[i - 1024] : bv[i - 2048]);
}

// ---------------------------------------------------------------------------
// row softmax: fp16 [rows,2048] -> fp16 [rows,2048], one block per row
// ---------------------------------------------------------------------------
__global__ __launch_bounds__(256) void softmax_kernel(
    const u16* __restrict__ S, u16* __restrict__ P)
{
    const long row = blockIdx.x;
    const int tid = threadIdx.x;

    union { uint4 v; u16 u[8]; } in;
    in.v = ((const uint4*)(S + row * SEQ))[tid];
    float f[8];
#pragma unroll
    for (int j = 0; j < 8; ++j) f[j] = h2f(in.u[j]);

    float m = fmaxf(fmaxf(fmaxf(f[0], f[1]), fmaxf(f[2], f[3])),
                    fmaxf(fmaxf(f[4], f[5]), fmaxf(f[6], f[7])));
#pragma unroll
    for (int off = 32; off; off >>= 1) m = fmaxf(m, __shfl_xor(m, off));

    __shared__ float rm[4], rs[4];
    if ((tid & 63) == 0) rm[tid >> 6] = m;
    __syncthreads();
    m = fmaxf(fmaxf(rm[0], rm[1]), fmaxf(rm[2], rm[3]));

    float e[8], s = 0.0f;
#pragma unroll
    for (int j = 0; j < 8; ++j) { e[j] = expf(f[j] - m); s += e[j]; }
#pragma unroll
    for (int off = 32; off; off >>= 1) s += __shfl_xor(s, off);
    if ((tid & 63) == 0) rs[tid >> 6] = s;
    __syncthreads();
    s = (rs[0] + rs[1]) + (rs[2] + rs[3]);

    const float inv = 1.0f / s;
    union { u16 u[8]; uint4 v; } pk;
#pragma unroll
    for (int j = 0; j < 8; ++j) pk.u[j] = f2h(e[j] * inv);
    *(uint4*)(P + row * SEQ + tid * 8) = pk.v;
}

// ---------------------------------------------------------------------------
// fused residual + layernorm; writes fp32 Xout and optional fp16 Xh
// ---------------------------------------------------------------------------
__global__ __launch_bounds__(256) void ln_kernel(
    const float* __restrict__ Ain, const float* __restrict__ Bin,
    const float* __restrict__ g, const float* __restrict__ be,
    float* __restrict__ Xout, u16* __restrict__ Xh)
{
    const long row = blockIdx.x;
    const int tid = threadIdx.x;

    const float4 a = ((const float4*)(Ain + row * EMB))[tid];
    const float4 b = ((const float4*)(Bin + row * EMB))[tid];
    const float h0 = a.x + b.x, h1 = a.y + b.y, h2 = a.z + b.z, h3 = a.w + b.w;

    float s = (h0 + h1) + (h2 + h3);
    float q = (h0 * h0 + h1 * h1) + (h2 * h2 + h3 * h3);
#pragma unroll
    for (int off = 32; off; off >>= 1) {
        s += __shfl_xor(s, off);
        q += __shfl_xor(q, off);
    }
    __shared__ float rsm[4], rqm[4];
    if ((tid & 63) == 0) { rsm[tid >> 6] = s; rqm[tid >> 6] = q; }
    __syncthreads();
    s = (rsm[0] + rsm[1]) + (rsm[2] + rsm[3]);
    q = (rqm[0] + rqm[1]) + (rqm[2] + rqm[3]);

    const float mu  = s * (1.0f / EMB);
    const float var = q * (1.0f / EMB) - mu * mu;
    const float rstd = rsqrtf(var + 1e-5f);

    const float4 gv = ((const float4*)g)[tid];
    const float4 bv = ((const float4*)be)[tid];
    const float y0 = (h0 - mu) * rstd * gv.x + bv.x;
    const float y1 = (h1 - mu) * rstd * gv.y + bv.y;
    const float y2 = (h2 - mu) * rstd * gv.z + bv.z;
    const float y3 = (h3 - mu) * rstd * gv.w + bv.w;

    ((float4*)(Xout + row * EMB))[tid] = make_float4(y0, y1, y2, y3);
    if (Xh) {
        union { u16 u[4]; uint2 v; } pk;
        pk.u[0] = f2h(y0); pk.u[1] = f2h(y1);
        pk.u[2] = f2h(y2); pk.u[3] = f2h(y3);
        ((uint2*)(Xh + row * EMB))[tid] = pk.v;
    }
}

// ---------------------------------------------------------------------------
extern "C" void kernel_launch(void* const* d_in, const int* in_sizes, int n_in,
                              void* d_out, int out_size, void* d_ws, size_t ws_size,
                              hipStream_t stream)
{
    const float* src = (const float*)d_in[0];
    const float* Wq  = (const float*)d_in[1];
    const float* bq  = (const float*)d_in[2];
    const float* Wk  = (const float*)d_in[3];
    const float* bk  = (const float*)d_in[4];
    const float* Wv  = (const float*)d_in[5];
    const float* bv  = (const float*)d_in[6];
    const float* Wo  = (const float*)d_in[7];
    const float* bo  = (const float*)d_in[8];
    const float* W1  = (const float*)d_in[9];
    const float* b1  = (const float*)d_in[10];
    const float* W2  = (const float*)d_in[11];
    const float* b2  = (const float*)d_in[12];
    const float* g1  = (const float*)d_in[13];
    const float* be1 = (const float*)d_in[14];
    const float* g2  = (const float*)d_in[15];
    const float* be2 = (const float*)d_in[16];
    float* out = (float*)d_out;

    char* ws = (char*)d_ws;
    const size_t MB = 1ull << 20;
    u16*   WqkvT   = (u16*)  (ws + 0 * MB);    // [3072,1024] 6MB
    u16*   WoT     = (u16*)  (ws + 6 * MB);    // [1024,1024] 2MB
    u16*   W1T     = (u16*)  (ws + 8 * MB);    // [4096,1024] 8MB
    u16*   W2T     = (u16*)  (ws + 16 * MB);   // [1024,4096] 8MB
    float* bqkv    = (float*)(ws + 24 * MB);   // [3072]
    u16*   Xh      = (u16*)  (ws + 25 * MB);   // [8192,1024] 16MB
    u16*   QKVh    = (u16*)  (ws + 41 * MB);   // [8192,3072] 48MB
    u16*   Vt      = (u16*)  (ws + 89 * MB);   // [4,1024,2048] 16MB
    u16*   scoresh = (u16*)  (ws + 105 * MB);  // [4,2048,2048] fp16 32MB
    u16*   P       = (u16*)  (ws + 137 * MB);  // [4,2048,2048] fp16 32MB
    u16*   attn    = (u16*)  (ws + 105 * MB);  // 16MB (scores dead after softmax)
    float* attnp   = (float*)(ws + 121 * MB);  // 32MB fp32
    float* x       = (float*)(ws + 153 * MB);  // 32MB fp32 (P dead after PV+Wo)
    u16*   xh      = (u16*)  (ws + 41 * MB);   // 16MB (QKVh dead after scores/Vt)
    u16*   ff1     = (u16*)  (ws + 57 * MB);   // [8192,4096] 64MB
    float* ff2     = (float*)(ws + 121 * MB);  // 32MB fp32 (attnp dead after LN1)
    // peak: 185MB

    const int M = BATCH * SEQ;                 // 8192
    const long SS = (long)SEQ * SEQ;           // 4M

    // 1) weights -> fp16 transposed (QKV concat into [3072,1024])
    transpose_cast<<<dim3(32, 32, 1), 256, 0, stream>>>(Wq, WqkvT, EMB, EMB);
    transpose_cast<<<dim3(32, 32, 1), 256, 0, stream>>>(Wk, WqkvT + 1024 * 1024, EMB, EMB);
    transpose_cast<<<dim3(32, 32, 1), 256, 0, stream>>>(Wv, WqkvT + 2048 * 1024, EMB, EMB);
    transpose_cast<<<dim3(32, 32, 1), 256, 0, stream>>>(Wo, WoT, EMB, EMB);
    transpose_cast<<<dim3(128, 32, 1), 256, 0, stream>>>(W1, W1T, EMB, FFD);
    transpose_cast<<<dim3(32, 128, 1), 256, 0, stream>>>(W2, W2T, FFD, EMB);
    concat_bias<<<dim3(12), 256, 0, stream>>>(bq, bk, bv, bqkv);

    // 2) src -> fp16
    cast_h<<<dim3((M * EMB) / (256 * 8)), 256, 0, stream>>>(src, Xh);

    // 3) fused QKV projection  [8192,3072]
    gemm_q<256, u16, false, true><<<dim3(32, 12, 1), 512, 0, stream>>>(
        Xh, WqkvT, QKVh, bqkv, 3072, 1024, 1024, 1024, 3072, 0, 0, 0);

    // 4) V -> Vt [B,E,S]
    transpose_h<<<dim3(32, 64, BATCH), 256, 0, stream>>>(
        QKVh + 2048, Vt, 3072, SEQ, (long)SEQ * 3072, (long)EMB * SEQ);

    // 5) scores = Q @ K^T per batch (fp16 out)
    gemm_q<256, u16, false, false><<<dim3(8, 8, BATCH), 512, 0, stream>>>(
        QKVh, QKVh + 1024, scoresh, nullptr, SEQ, EMB, 3072, 3072, SEQ,
        (long)SEQ * 3072, (long)SEQ * 3072, SS);

    // 6) softmax -> P fp16
    softmax_kernel<<<dim3(M), 256, 0, stream>>>(scoresh, P);

    // 7) attn = P @ Vt^T per batch
    gemm_s<128, u16, false, false><<<dim3(16, 4, BATCH), 512, 0, stream>>>(
        P, Vt, attn, nullptr, EMB, SEQ, SEQ, SEQ, EMB,
        SS, (long)EMB * SEQ, (long)SEQ * EMB);

    // 8) attnp = attn @ Wo^T + bo
    gemm_s<128, float, false, true><<<dim3(64, 4, 1), 512, 0, stream>>>(
        attn, WoT, attnp, bo, EMB, EMB, EMB, EMB, EMB, 0, 0, 0);

    // 9) x = LN1(src + attnp); also xh fp16
    ln_kernel<<<dim3(M), 256, 0, stream>>>(src, attnp, g1, be1, x, xh);

    // 10) ff1 = relu(x @ W1^T + b1)
    gemm_q<256, u16, true, true><<<dim3(32, 16, 1), 512, 0, stream>>>(
        xh, W1T, ff1, b1, FFD, EMB, EMB, EMB, FFD, 0, 0, 0);

    // 11) ff2 = ff1 @ W2^T + b2
    gemm_s<128, float, false, true><<<dim3(64, 4, 1), 512, 0, stream>>>(
        ff1, W2T, ff2, b2, EMB, FFD, FFD, FFD, EMB, 0, 0, 0);

    // 12) out = LN2(x + ff2)
    ln_kernel<<<dim3(M), 256, 0, stream>>>(x, ff2, g2, be2, out, nullptr);
}